// Round 1
// baseline (1272.436 us; speedup 1.0000x reference)
//
#include <hip/hip_runtime.h>

#define B 8
#define C 64
#define H 128
#define W 128
#define HW (H * W)
#define OC 27
#define KK 9
#define COUT 64

// ---------------------------------------------------------------------------
// Kernel 1: transpose x (NCHW) -> xT (NHWC), LDS-tiled 64x64 so both global
// read and write are coalesced.  2048 blocks x 256 threads.
// ---------------------------------------------------------------------------
__global__ __launch_bounds__(256) void k_transpose_x(const float* __restrict__ x,
                                                     float* __restrict__ xT) {
    __shared__ float lds[64][65];  // +1 pad: conflict-free both phases
    int b = blockIdx.x >> 8;       // 256 hw-tiles per batch (HW/64 = 256)
    int tile = blockIdx.x & 255;
    int hw0 = tile * 64;
    int lane = threadIdx.x & 63;
    int cg = threadIdx.x >> 6;  // 0..3
#pragma unroll
    for (int r = 0; r < 16; ++r) {
        int c = cg * 16 + r;
        lds[c][lane] = x[(size_t)(b * C + c) * HW + hw0 + lane];  // coalesced over hw
    }
    __syncthreads();
#pragma unroll
    for (int r = 0; r < 16; ++r) {
        int hwl = cg * 16 + r;
        xT[(size_t)(b * HW + hw0 + hwl) * C + lane] = lds[lane][hwl];  // coalesced over c
    }
}

// ---------------------------------------------------------------------------
// Kernel 2: transpose w (Cout,C,3,3) -> wT[k][c][o]  (tiny: 36864 elems)
// ---------------------------------------------------------------------------
__global__ __launch_bounds__(256) void k_transpose_w(const float* __restrict__ w,
                                                     float* __restrict__ wT) {
    int idx = blockIdx.x * 256 + threadIdx.x;  // idx = (k*64 + c)*64 + o
    if (idx >= KK * C * COUT) return;
    int o = idx & 63;
    int c = (idx >> 6) & 63;
    int k = idx >> 12;
    wT[idx] = w[(size_t)(o * C + c) * KK + k];
}

// ---------------------------------------------------------------------------
// Kernel 3: offset/mask conv: om[b][oc][h][w], oc in [0,27).
// Thread per output, w fastest -> x reads coalesced, ow reads wave-uniform.
// ---------------------------------------------------------------------------
__global__ __launch_bounds__(256) void k_om(const float* __restrict__ x,
                                            const float* __restrict__ ow,
                                            const float* __restrict__ ob,
                                            float* __restrict__ om) {
    int gid = blockIdx.x * 256 + threadIdx.x;   // ((b*27+oc)*H + h)*W + w
    int w = gid & (W - 1);
    int h = (gid >> 7) & (H - 1);
    int oc = (gid >> 14) % OC;
    int b = gid / (OC * HW);
    float acc = ob[oc];
    const float* wr = ow + (size_t)oc * (C * KK);
    const float* xb = x + (size_t)b * (C * HW);
    for (int c = 0; c < C; ++c) {
        const float* xc = xb + c * HW;
        const float* wc = wr + c * KK;
#pragma unroll
        for (int kh = 0; kh < 3; ++kh) {
            int y = h + kh - 1;
            if ((unsigned)y >= H) continue;
            const float* row = xc + y * W;
#pragma unroll
            for (int kw = 0; kw < 3; ++kw) {
                int xx = w + kw - 1;
                float xv = ((unsigned)xx < W) ? row[xx] : 0.0f;
                acc = fmaf(xv, wc[kh * 3 + kw], acc);
            }
        }
    }
    om[gid] = acc;
}

// ---------------------------------------------------------------------------
// Kernel 4: fused deformable sampling + einsum.
// One wave handles 8 consecutive pixels (same row).
//   Phase A (lane = channel c): samp[p][k] via coalesced NHWC corner gathers.
//   Phase B (lane = out-chan o): acc[p] += wT[k][c][o] * readlane(samp[p][k], c)
// readlane with uniform c = 1 VALU op, no LDS traffic; weight load amortized
// over 8 pixels.
// ---------------------------------------------------------------------------
__global__ __launch_bounds__(256, 1) void k_main(const float* __restrict__ xT,
                                                 const float* __restrict__ om,
                                                 const float* __restrict__ wT,
                                                 const float* __restrict__ bias,
                                                 float* __restrict__ out) {
    int lane = threadIdx.x & 63;
    int wv = threadIdx.x >> 6;
    int gw = blockIdx.x * 4 + wv;  // global wave id
    int pb = gw * 8;               // first pixel (linear over B*H*W, w fastest)
    int b = pb >> 14;              // / HW
    int rem = pb & (HW - 1);
    int h = rem >> 7;
    int w0 = rem & (W - 1);

    const float* xb = xT + (size_t)b * (HW * C);
    const float* omb = om + (size_t)b * (OC * HW);
    int hw_off = h * W + w0;

    float samp[8][KK];
#pragma unroll
    for (int p = 0; p < 8; ++p) {
#pragma unroll
        for (int k = 0; k < KK; ++k) {
            int dh = k / 3 - 1;
            int dw = k % 3 - 1;
            float offx = omb[(size_t)k * HW + hw_off + p];
            float offy = omb[(size_t)(KK + k) * HW + hw_off + p];
            float mlog = omb[(size_t)(2 * KK + k) * HW + hw_off + p];
            float mask = 1.0f / (1.0f + __expf(-mlog));
            float gx = (float)(w0 + p + dw) + offx;
            float gy = (float)(h + dh) + offy;
            float x0f = floorf(gx), y0f = floorf(gy);
            int x0 = (int)x0f, y0 = (int)y0f;
            int x1 = x0 + 1, y1 = y0 + 1;
            float wx1 = gx - x0f, wy1 = gy - y0f;
            float wx0 = 1.0f - wx1, wy0 = 1.0f - wy1;
            float acc = 0.0f;
            if ((unsigned)y0 < H) {
                const float* row = xb + (size_t)(y0 * W) * C;
                if ((unsigned)x0 < W) acc = fmaf(wy0 * wx0, row[x0 * C + lane], acc);
                if ((unsigned)x1 < W) acc = fmaf(wy0 * wx1, row[x1 * C + lane], acc);
            }
            if ((unsigned)y1 < H) {
                const float* row = xb + (size_t)(y1 * W) * C;
                if ((unsigned)x0 < W) acc = fmaf(wy1 * wx0, row[x0 * C + lane], acc);
                if ((unsigned)x1 < W) acc = fmaf(wy1 * wx1, row[x1 * C + lane], acc);
            }
            samp[p][k] = acc * mask;
        }
    }

    // Phase B: lane = output channel o
    float acc[8];
    float bo = bias[lane];
#pragma unroll
    for (int p = 0; p < 8; ++p) acc[p] = bo;

#pragma unroll
    for (int k = 0; k < KK; ++k) {
        const float* wk = wT + (size_t)k * (C * COUT);
        for (int c = 0; c < C; ++c) {  // c is wave-uniform -> SGPR readlane idx
            float wval = wk[c * COUT + lane];
#pragma unroll
            for (int p = 0; p < 8; ++p) {
                float sv = __int_as_float(
                    __builtin_amdgcn_readlane(__float_as_int(samp[p][k]), c));
                acc[p] = fmaf(wval, sv, acc[p]);
            }
        }
    }

#pragma unroll
    for (int p = 0; p < 8; ++p) {
        out[((size_t)(b * COUT + lane) * H + h) * W + w0 + p] = acc[p];
    }
}

// ---------------------------------------------------------------------------
extern "C" void kernel_launch(void* const* d_in, const int* in_sizes, int n_in,
                              void* d_out, int out_size, void* d_ws, size_t ws_size,
                              hipStream_t stream) {
    const float* x = (const float*)d_in[0];
    const float* ow = (const float*)d_in[1];
    const float* ob = (const float*)d_in[2];
    const float* w = (const float*)d_in[3];
    const float* bias = (const float*)d_in[4];
    float* out = (float*)d_out;

    float* ws = (float*)d_ws;
    float* xT = ws;                                  // B*HW*C      = 8388608 f
    float* om = xT + (size_t)B * HW * C;             // B*27*HW     = 3538944 f
    float* wT = om + (size_t)B * OC * HW;            // 9*64*64     = 36864 f
    // total ~47.9 MB of workspace

    hipLaunchKernelGGL(k_transpose_x, dim3(B * 256), dim3(256), 0, stream, x, xT);
    hipLaunchKernelGGL(k_transpose_w, dim3((KK * C * COUT + 255) / 256), dim3(256), 0,
                       stream, w, wT);
    hipLaunchKernelGGL(k_om, dim3(B * OC * HW / 256), dim3(256), 0, stream, x, ow, ob, om);
    hipLaunchKernelGGL(k_main, dim3(B * HW / 32), dim3(256), 0, stream, xT, om, wT, bias, out);
}

// Round 2
// 904.555 us; speedup vs baseline: 1.4067x; 1.4067x over previous
//
#include <hip/hip_runtime.h>

#define B 8
#define C 64
#define H 128
#define W 128
#define HW (H * W)
#define OC 27
#define KK 9
#define COUT 64
#define CSTEP 2

// ---------------------------------------------------------------------------
// Kernel 1: transpose x (NCHW) -> xT (NHWC), LDS-tiled 64x64 so both global
// read and write are coalesced.  2048 blocks x 256 threads.
// ---------------------------------------------------------------------------
__global__ __launch_bounds__(256) void k_transpose_x(const float* __restrict__ x,
                                                     float* __restrict__ xT) {
    __shared__ float lds[64][65];  // +1 pad: conflict-free both phases
    int b = blockIdx.x >> 8;       // 256 hw-tiles per batch (HW/64 = 256)
    int tile = blockIdx.x & 255;
    int hw0 = tile * 64;
    int lane = threadIdx.x & 63;
    int cg = threadIdx.x >> 6;  // 0..3
#pragma unroll
    for (int r = 0; r < 16; ++r) {
        int c = cg * 16 + r;
        lds[c][lane] = x[(size_t)(b * C + c) * HW + hw0 + lane];  // coalesced over hw
    }
    __syncthreads();
#pragma unroll
    for (int r = 0; r < 16; ++r) {
        int hwl = cg * 16 + r;
        xT[(size_t)(b * HW + hw0 + hwl) * C + lane] = lds[lane][hwl];  // coalesced over c
    }
}

// ---------------------------------------------------------------------------
// Kernel 2: transpose w (Cout,C,3,3) -> wT[k][c][o]  (tiny: 36864 elems)
// ---------------------------------------------------------------------------
__global__ __launch_bounds__(256) void k_transpose_w(const float* __restrict__ w,
                                                     float* __restrict__ wT) {
    int idx = blockIdx.x * 256 + threadIdx.x;  // idx = (k*64 + c)*64 + o
    if (idx >= KK * C * COUT) return;
    int o = idx & 63;
    int c = (idx >> 6) & 63;
    int k = idx >> 12;
    wT[idx] = w[(size_t)(o * C + c) * KK + k];
}

// ---------------------------------------------------------------------------
// Kernel 2b: transpose ow (27,C,3,3) -> owT[c][oc][k]  (15552 elems) so the
// per-channel weight slab (27*9 floats) is contiguous -> wave-uniform s_loads.
// ---------------------------------------------------------------------------
__global__ __launch_bounds__(256) void k_transpose_ow(const float* __restrict__ ow,
                                                      float* __restrict__ owT) {
    int idx = blockIdx.x * 256 + threadIdx.x;  // idx = (c*27 + oc)*9 + k
    if (idx >= OC * C * KK) return;
    int k = idx % KK;
    int oc = (idx / KK) % OC;
    int c = idx / (KK * OC);
    owT[idx] = ow[(size_t)(oc * C + c) * KK + k];
}

// ---------------------------------------------------------------------------
// Kernel 3 (rewritten): offset/mask conv, om[b][oc][h][w].
// Block = 2 rows x 128 cols (256 threads), computes ALL 27 oc per pixel.
// Per 2-channel step: stage 4 x-rows in LDS (coalesced), each thread reads
// its 3x3 window once (9 LDS reads) and does 2*243 FMAs with scalar-pipe
// weight loads from contiguous owT[c] slabs. FMA:mem ratio 27:1.
// ---------------------------------------------------------------------------
__global__ __launch_bounds__(256) void k_om(const float* __restrict__ x,
                                            const float* __restrict__ owT,
                                            const float* __restrict__ ob,
                                            float* __restrict__ om) {
    __shared__ float xs[CSTEP][4][128];
    int blk = blockIdx.x;  // b*64 + rowpair
    int b = blk >> 6;
    int h0 = (blk & 63) * 2;
    int tid = threadIdx.x;
    int r = tid >> 7;       // 0..1
    int wcol = tid & 127;
    int h = h0 + r;

    float acc[OC];
#pragma unroll
    for (int oc = 0; oc < OC; ++oc) acc[oc] = ob[oc];

    const float* xb = x + (size_t)b * (C * HW);

    for (int c0 = 0; c0 < C; c0 += CSTEP) {
        __syncthreads();  // WAR: previous iter's reads done before overwrite
#pragma unroll
        for (int i = 0; i < 2 * CSTEP; ++i) {
            int idx = i * 256 + tid;  // 0 .. 512*CSTEP-1
            int cc = idx >> 9;        // /512
            int rr = (idx >> 7) & 3;
            int col = idx & 127;
            int y = h0 - 1 + rr;
            float v = 0.0f;
            if ((unsigned)y < H) v = xb[(size_t)(c0 + cc) * HW + y * W + col];
            xs[cc][rr][col] = v;
        }
        __syncthreads();
#pragma unroll
        for (int cc = 0; cc < CSTEP; ++cc) {
            const float* wc = owT + (size_t)(c0 + cc) * (OC * KK);  // uniform
            float xv[9];
#pragma unroll
            for (int dr = 0; dr < 3; ++dr)
#pragma unroll
                for (int dw = 0; dw < 3; ++dw) {
                    int col = wcol - 1 + dw;
                    xv[dr * 3 + dw] = ((unsigned)col < W) ? xs[cc][r + dr][col] : 0.0f;
                }
#pragma unroll
            for (int oc = 0; oc < OC; ++oc) {
#pragma unroll
                for (int k = 0; k < KK; ++k)
                    acc[oc] = fmaf(wc[oc * KK + k], xv[k], acc[oc]);
            }
        }
    }
#pragma unroll
    for (int oc = 0; oc < OC; ++oc)
        om[(((size_t)b * OC + oc) * H + h) * W + wcol] = acc[oc];  // coalesced over w
}

// ---------------------------------------------------------------------------
// Kernel 4: fused deformable sampling + einsum (unchanged this round).
// ---------------------------------------------------------------------------
__global__ __launch_bounds__(256, 1) void k_main(const float* __restrict__ xT,
                                                 const float* __restrict__ om,
                                                 const float* __restrict__ wT,
                                                 const float* __restrict__ bias,
                                                 float* __restrict__ out) {
    int lane = threadIdx.x & 63;
    int wv = threadIdx.x >> 6;
    int gw = blockIdx.x * 4 + wv;  // global wave id
    int pb = gw * 8;               // first pixel (linear over B*H*W, w fastest)
    int b = pb >> 14;              // / HW
    int rem = pb & (HW - 1);
    int h = rem >> 7;
    int w0 = rem & (W - 1);

    const float* xb = xT + (size_t)b * (HW * C);
    const float* omb = om + (size_t)b * (OC * HW);
    int hw_off = h * W + w0;

    float samp[8][KK];
#pragma unroll
    for (int p = 0; p < 8; ++p) {
#pragma unroll
        for (int k = 0; k < KK; ++k) {
            int dh = k / 3 - 1;
            int dw = k % 3 - 1;
            float offx = omb[(size_t)k * HW + hw_off + p];
            float offy = omb[(size_t)(KK + k) * HW + hw_off + p];
            float mlog = omb[(size_t)(2 * KK + k) * HW + hw_off + p];
            float mask = 1.0f / (1.0f + __expf(-mlog));
            float gx = (float)(w0 + p + dw) + offx;
            float gy = (float)(h + dh) + offy;
            float x0f = floorf(gx), y0f = floorf(gy);
            int x0 = (int)x0f, y0 = (int)y0f;
            int x1 = x0 + 1, y1 = y0 + 1;
            float wx1 = gx - x0f, wy1 = gy - y0f;
            float wx0 = 1.0f - wx1, wy0 = 1.0f - wy1;
            float acc = 0.0f;
            if ((unsigned)y0 < H) {
                const float* row = xb + (size_t)(y0 * W) * C;
                if ((unsigned)x0 < W) acc = fmaf(wy0 * wx0, row[x0 * C + lane], acc);
                if ((unsigned)x1 < W) acc = fmaf(wy0 * wx1, row[x1 * C + lane], acc);
            }
            if ((unsigned)y1 < H) {
                const float* row = xb + (size_t)(y1 * W) * C;
                if ((unsigned)x0 < W) acc = fmaf(wy1 * wx0, row[x0 * C + lane], acc);
                if ((unsigned)x1 < W) acc = fmaf(wy1 * wx1, row[x1 * C + lane], acc);
            }
            samp[p][k] = acc * mask;
        }
    }

    // Phase B: lane = output channel o
    float acc[8];
    float bo = bias[lane];
#pragma unroll
    for (int p = 0; p < 8; ++p) acc[p] = bo;

#pragma unroll
    for (int k = 0; k < KK; ++k) {
        const float* wk = wT + (size_t)k * (C * COUT);
        for (int c = 0; c < C; ++c) {  // c is wave-uniform -> SGPR readlane idx
            float wval = wk[c * COUT + lane];
#pragma unroll
            for (int p = 0; p < 8; ++p) {
                float sv = __int_as_float(
                    __builtin_amdgcn_readlane(__float_as_int(samp[p][k]), c));
                acc[p] = fmaf(wval, sv, acc[p]);
            }
        }
    }

#pragma unroll
    for (int p = 0; p < 8; ++p) {
        out[((size_t)(b * COUT + lane) * H + h) * W + w0 + p] = acc[p];
    }
}

// ---------------------------------------------------------------------------
extern "C" void kernel_launch(void* const* d_in, const int* in_sizes, int n_in,
                              void* d_out, int out_size, void* d_ws, size_t ws_size,
                              hipStream_t stream) {
    const float* x = (const float*)d_in[0];
    const float* ow = (const float*)d_in[1];
    const float* ob = (const float*)d_in[2];
    const float* w = (const float*)d_in[3];
    const float* bias = (const float*)d_in[4];
    float* out = (float*)d_out;

    float* ws = (float*)d_ws;
    float* xT = ws;                                  // B*HW*C      = 8388608 f
    float* om = xT + (size_t)B * HW * C;             // B*27*HW     = 3538944 f
    float* wT = om + (size_t)B * OC * HW;            // 9*64*64     = 36864 f
    float* owT = wT + (size_t)KK * C * COUT;         // 27*64*9     = 15552 f
    // total ~48 MB of workspace

    hipLaunchKernelGGL(k_transpose_x, dim3(B * 256), dim3(256), 0, stream, x, xT);
    hipLaunchKernelGGL(k_transpose_w, dim3((KK * C * COUT + 255) / 256), dim3(256), 0,
                       stream, w, wT);
    hipLaunchKernelGGL(k_transpose_ow, dim3((OC * C * KK + 255) / 256), dim3(256), 0,
                       stream, ow, owT);
    hipLaunchKernelGGL(k_om, dim3(B * H / 2), dim3(256), 0, stream, x, owT, ob, om);
    hipLaunchKernelGGL(k_main, dim3(B * HW / 32), dim3(256), 0, stream, xT, om, wT, bias, out);
}

// Round 3
// 615.584 us; speedup vs baseline: 2.0670x; 1.4694x over previous
//
#include <hip/hip_runtime.h>

#define B 8
#define C 64
#define H 128
#define W 128
#define HW (H * W)
#define OC 27
#define KK 9
#define COUT 64
#define CSTEP 2
#define KDIM 576           // 9*64
#define LDSROW 1152        // bytes per pixel row (576 * 2B)
#define NPIX 32            // pixels per workgroup

typedef __attribute__((ext_vector_type(8))) short s16x8;
typedef __attribute__((ext_vector_type(4))) float f32x4;

// ---------------------------------------------------------------------------
// Kernel 1: transpose x (NCHW) -> xT (NHWC) for coalesced channel gathers.
// ---------------------------------------------------------------------------
__global__ __launch_bounds__(256) void k_transpose_x(const float* __restrict__ x,
                                                     float* __restrict__ xT) {
    __shared__ float lds[64][65];
    int b = blockIdx.x >> 8;
    int tile = blockIdx.x & 255;
    int hw0 = tile * 64;
    int lane = threadIdx.x & 63;
    int cg = threadIdx.x >> 6;
#pragma unroll
    for (int r = 0; r < 16; ++r) {
        int c = cg * 16 + r;
        lds[c][lane] = x[(size_t)(b * C + c) * HW + hw0 + lane];
    }
    __syncthreads();
#pragma unroll
    for (int r = 0; r < 16; ++r) {
        int hwl = cg * 16 + r;
        xT[(size_t)(b * HW + hw0 + hwl) * C + lane] = lds[lane][hwl];
    }
}

// ---------------------------------------------------------------------------
// Kernel 2: repack w (Cout,C,3,3) fp32 -> wB[o][K] bf16, K = k*64 + c.
// ---------------------------------------------------------------------------
__global__ __launch_bounds__(256) void k_prep_w(const float* __restrict__ w,
                                                ushort* __restrict__ wB) {
    int idx = blockIdx.x * 256 + threadIdx.x;  // o*576 + K
    if (idx >= COUT * KDIM) return;
    int o = idx / KDIM;
    int Kx = idx % KDIM;
    int k = Kx >> 6;
    int c = Kx & 63;
    float v = w[(size_t)(o * C + c) * KK + k];
    union { float f; unsigned u; } uv;
    uv.f = v;
    // round-to-nearest-even bf16
    unsigned r = uv.u + 0x7FFF + ((uv.u >> 16) & 1);
    wB[idx] = (ushort)(r >> 16);
}

// ---------------------------------------------------------------------------
// Kernel 2b: transpose ow (27,C,3,3) -> owT[c][oc][k] for wave-uniform s_loads.
// ---------------------------------------------------------------------------
__global__ __launch_bounds__(256) void k_transpose_ow(const float* __restrict__ ow,
                                                      float* __restrict__ owT) {
    int idx = blockIdx.x * 256 + threadIdx.x;  // (c*27 + oc)*9 + k
    if (idx >= OC * C * KK) return;
    int k = idx % KK;
    int oc = (idx / KK) % OC;
    int c = idx / (KK * OC);
    owT[idx] = ow[(size_t)(oc * C + c) * KK + k];
}

// ---------------------------------------------------------------------------
// Kernel 3: offset/mask conv (unchanged this round).
// ---------------------------------------------------------------------------
__global__ __launch_bounds__(256) void k_om(const float* __restrict__ x,
                                            const float* __restrict__ owT,
                                            const float* __restrict__ ob,
                                            float* __restrict__ om) {
    __shared__ float xs[CSTEP][4][128];
    int blk = blockIdx.x;
    int b = blk >> 6;
    int h0 = (blk & 63) * 2;
    int tid = threadIdx.x;
    int r = tid >> 7;
    int wcol = tid & 127;
    int h = h0 + r;

    float acc[OC];
#pragma unroll
    for (int oc = 0; oc < OC; ++oc) acc[oc] = ob[oc];

    const float* xb = x + (size_t)b * (C * HW);

    for (int c0 = 0; c0 < C; c0 += CSTEP) {
        __syncthreads();
#pragma unroll
        for (int i = 0; i < 2 * CSTEP; ++i) {
            int idx = i * 256 + tid;
            int cc = idx >> 9;
            int rr = (idx >> 7) & 3;
            int col = idx & 127;
            int y = h0 - 1 + rr;
            float v = 0.0f;
            if ((unsigned)y < H) v = xb[(size_t)(c0 + cc) * HW + y * W + col];
            xs[cc][rr][col] = v;
        }
        __syncthreads();
#pragma unroll
        for (int cc = 0; cc < CSTEP; ++cc) {
            const float* wc = owT + (size_t)(c0 + cc) * (OC * KK);
            float xv[9];
#pragma unroll
            for (int dr = 0; dr < 3; ++dr)
#pragma unroll
                for (int dw = 0; dw < 3; ++dw) {
                    int col = wcol - 1 + dw;
                    xv[dr * 3 + dw] = ((unsigned)col < W) ? xs[cc][r + dr][col] : 0.0f;
                }
#pragma unroll
            for (int oc = 0; oc < OC; ++oc) {
#pragma unroll
                for (int k = 0; k < KK; ++k)
                    acc[oc] = fmaf(wc[oc * KK + k], xv[k], acc[oc]);
            }
        }
    }
#pragma unroll
    for (int oc = 0; oc < OC; ++oc)
        om[(((size_t)b * OC + oc) * H + h) * W + wcol] = acc[oc];
}

// ---------------------------------------------------------------------------
// Kernel 4: fused deformable sampling + MFMA einsum.
// Workgroup = 4 waves, 32 consecutive pixels (one row segment).
// Phase A (lane=c): each wave samples 8 pixels x 9 taps -> bf16 LDS
//   samp[pix][K], K = tap*64 + c, XOR-swizzled by ((pix&7)<<4).
// Phase B: wave wv owns o-rows [wv*16, wv*16+16): A-frags (weights) in 72
//   VGPRs, 2 N-blocks x 18 K-steps of mfma_f32_16x16x32_bf16.
// ---------------------------------------------------------------------------
__global__ __launch_bounds__(256) void k_main(const float* __restrict__ xT,
                                              const float* __restrict__ om,
                                              const ushort* __restrict__ wB,
                                              const float* __restrict__ bias,
                                              float* __restrict__ out) {
    __shared__ __align__(16) char smem[NPIX * LDSROW];  // 36864 B
    int lane = threadIdx.x & 63;
    int wv = threadIdx.x >> 6;
    int pb = blockIdx.x * NPIX;
    int b = pb >> 14;
    int rem = pb & (HW - 1);
    int h = rem >> 7;
    int w0 = rem & (W - 1);  // 0,32,64,96

    const float* xb = xT + (size_t)b * (HW * C);
    const float* omb = om + (size_t)b * (OC * HW) + h * W + w0;

    // ---- Phase A: sample pixels [wv*8, wv*8+8), lane = channel ----
    for (int p = wv * 8; p < wv * 8 + 8; ++p) {
        int swz = (p & 7) << 4;
#pragma unroll
        for (int k = 0; k < KK; ++k) {
            int dh = k / 3 - 1;
            int dw = k % 3 - 1;
            float offx = omb[(size_t)k * HW + p];
            float offy = omb[(size_t)(KK + k) * HW + p];
            float mlog = omb[(size_t)(2 * KK + k) * HW + p];
            float mask = 1.0f / (1.0f + __expf(-mlog));
            float gx = (float)(w0 + p + dw) + offx;
            float gy = (float)(h + dh) + offy;
            float x0f = floorf(gx), y0f = floorf(gy);
            int x0 = (int)x0f, y0 = (int)y0f;
            int x1 = x0 + 1, y1 = y0 + 1;
            float wx1 = gx - x0f, wy1 = gy - y0f;
            float wx0 = 1.0f - wx1, wy0 = 1.0f - wy1;
            float acc = 0.0f;
            if ((unsigned)y0 < H) {
                const float* row = xb + (size_t)(y0 * W) * C;
                if ((unsigned)x0 < W) acc = fmaf(wy0 * wx0, row[x0 * C + lane], acc);
                if ((unsigned)x1 < W) acc = fmaf(wy0 * wx1, row[x1 * C + lane], acc);
            }
            if ((unsigned)y1 < H) {
                const float* row = xb + (size_t)(y1 * W) * C;
                if ((unsigned)x0 < W) acc = fmaf(wy1 * wx0, row[x0 * C + lane], acc);
                if ((unsigned)x1 < W) acc = fmaf(wy1 * wx1, row[x1 * C + lane], acc);
            }
            float val = acc * mask;
            // bf16 round-to-nearest-even
            union { float f; unsigned u; } uv;
            uv.f = val;
            unsigned rr = uv.u + 0x7FFF + ((uv.u >> 16) & 1);
            ushort bv = (ushort)(rr >> 16);
            int byte = (p * LDSROW + (k * 64 + lane) * 2) ^ swz;
            *(ushort*)(smem + byte) = bv;
        }
    }

    // ---- load A-fragments (weights for this wave's 16 o-rows) ----
    s16x8 afrag[18];
    {
        const ushort* wrow = wB + (size_t)(wv * 16 + (lane & 15)) * KDIM;
#pragma unroll
        for (int s = 0; s < 18; ++s)
            afrag[s] = *(const s16x8*)(wrow + s * 32 + (lane >> 4) * 8);
    }

    __syncthreads();

    // ---- Phase B: MFMA ----
    f32x4 acc0, acc1;
#pragma unroll
    for (int j = 0; j < 4; ++j) {
        float bvv = bias[wv * 16 + (lane >> 4) * 4 + j];
        acc0[j] = bvv;
        acc1[j] = bvv;
    }

#pragma unroll
    for (int s = 0; s < 18; ++s) {
        int kbyte = s * 64 + (lane >> 4) * 16;
        {
            int pix = (lane & 15);
            int byte = (pix * LDSROW + kbyte) ^ ((pix & 7) << 4);
            s16x8 bfrag = *(const s16x8*)(smem + byte);
            acc0 = __builtin_amdgcn_mfma_f32_16x16x32_bf16(afrag[s], bfrag, acc0, 0, 0, 0);
        }
        {
            int pix = 16 + (lane & 15);
            int byte = (pix * LDSROW + kbyte) ^ ((pix & 7) << 4);
            s16x8 bfrag = *(const s16x8*)(smem + byte);
            acc1 = __builtin_amdgcn_mfma_f32_16x16x32_bf16(afrag[s], bfrag, acc1, 0, 0, 0);
        }
    }

    // ---- C write: o = wv*16 + (lane>>4)*4 + j, pix = nb*16 + (lane&15) ----
    float* obase = out + ((size_t)(b * COUT + wv * 16 + (lane >> 4) * 4) * HW) + h * W + w0;
#pragma unroll
    for (int j = 0; j < 4; ++j) {
        obase[(size_t)j * HW + (lane & 15)] = acc0[j];
        obase[(size_t)j * HW + 16 + (lane & 15)] = acc1[j];
    }
}

// ---------------------------------------------------------------------------
extern "C" void kernel_launch(void* const* d_in, const int* in_sizes, int n_in,
                              void* d_out, int out_size, void* d_ws, size_t ws_size,
                              hipStream_t stream) {
    const float* x = (const float*)d_in[0];
    const float* ow = (const float*)d_in[1];
    const float* ob = (const float*)d_in[2];
    const float* w = (const float*)d_in[3];
    const float* bias = (const float*)d_in[4];
    float* out = (float*)d_out;

    float* ws = (float*)d_ws;
    float* xT = ws;                                  // 8388608 f
    float* om = xT + (size_t)B * HW * C;             // 3538944 f
    float* owT = om + (size_t)B * OC * HW;           // 15552 f
    ushort* wB = (ushort*)(owT + (size_t)OC * C * KK);  // 36864 ushort

    hipLaunchKernelGGL(k_transpose_x, dim3(B * 256), dim3(256), 0, stream, x, xT);
    hipLaunchKernelGGL(k_prep_w, dim3((COUT * KDIM + 255) / 256), dim3(256), 0,
                       stream, w, wB);
    hipLaunchKernelGGL(k_transpose_ow, dim3((OC * C * KK + 255) / 256), dim3(256), 0,
                       stream, ow, owT);
    hipLaunchKernelGGL(k_om, dim3(B * H / 2), dim3(256), 0, stream, x, owT, ob, om);
    hipLaunchKernelGGL(k_main, dim3(B * HW / NPIX), dim3(256), 0, stream, xT, om, wB, bias, out);
}

// Round 4
// 270.996 us; speedup vs baseline: 4.6954x; 2.2716x over previous
//
#include <hip/hip_runtime.h>

#define B 8
#define C 64
#define H 128
#define W 128
#define HW (H * W)
#define OC 27
#define KK 9
#define COUT 64
#define CSTEP 2
#define KDIM 576           // 9*64
#define LDSROW 1152        // bytes per pixel row (576 * 2B)
#define NPIX 16            // pixels per workgroup
#define NPAIR (NPIX * KK)  // 144

typedef __attribute__((ext_vector_type(8))) short s16x8;
typedef __attribute__((ext_vector_type(4))) float f32x4;

__device__ inline ushort f2bf(float f) {
    union { float f; unsigned u; } uv;
    uv.f = f;
    unsigned r = uv.u + 0x7FFF + ((uv.u >> 16) & 1);
    return (ushort)(r >> 16);
}
__device__ inline float bf2f(ushort u) {
    return __uint_as_float((unsigned)u << 16);
}

// ---------------------------------------------------------------------------
// Kernel 1: transpose x (NCHW fp32) -> xTb (NHWC bf16).
// ---------------------------------------------------------------------------
__global__ __launch_bounds__(256) void k_transpose_x(const float* __restrict__ x,
                                                     ushort* __restrict__ xTb) {
    __shared__ float lds[64][65];
    int b = blockIdx.x >> 8;
    int tile = blockIdx.x & 255;
    int hw0 = tile * 64;
    int lane = threadIdx.x & 63;
    int cg = threadIdx.x >> 6;
#pragma unroll
    for (int r = 0; r < 16; ++r) {
        int c = cg * 16 + r;
        lds[c][lane] = x[(size_t)(b * C + c) * HW + hw0 + lane];
    }
    __syncthreads();
#pragma unroll
    for (int r = 0; r < 16; ++r) {
        int hwl = cg * 16 + r;
        xTb[(size_t)(b * HW + hw0 + hwl) * C + lane] = f2bf(lds[lane][hwl]);
    }
}

// ---------------------------------------------------------------------------
// Kernel 2: repack w (Cout,C,3,3) fp32 -> wB[o][K] bf16, K = k*64 + c.
// ---------------------------------------------------------------------------
__global__ __launch_bounds__(256) void k_prep_w(const float* __restrict__ w,
                                                ushort* __restrict__ wB) {
    int idx = blockIdx.x * 256 + threadIdx.x;
    if (idx >= COUT * KDIM) return;
    int o = idx / KDIM;
    int Kx = idx % KDIM;
    int k = Kx >> 6;
    int c = Kx & 63;
    wB[idx] = f2bf(w[(size_t)(o * C + c) * KK + k]);
}

// ---------------------------------------------------------------------------
// Kernel 2b: transpose ow (27,C,3,3) -> owT[c][oc][k] (fp32, wave-uniform).
// ---------------------------------------------------------------------------
__global__ __launch_bounds__(256) void k_transpose_ow(const float* __restrict__ ow,
                                                      float* __restrict__ owT) {
    int idx = blockIdx.x * 256 + threadIdx.x;
    if (idx >= OC * C * KK) return;
    int k = idx % KK;
    int oc = (idx / KK) % OC;
    int c = idx / (KK * OC);
    owT[idx] = ow[(size_t)(oc * C + c) * KK + k];
}

// ---------------------------------------------------------------------------
// Kernel 3: offset/mask conv, channel-split x2 for occupancy, reg-prefetch
// double buffering. omp[split][b][oc][h][w]; split 0 carries the bias.
// ---------------------------------------------------------------------------
__global__ __launch_bounds__(256) void k_om(const float* __restrict__ x,
                                            const float* __restrict__ owT,
                                            const float* __restrict__ ob,
                                            float* __restrict__ omp) {
    __shared__ float xs[CSTEP * 4 * 128];
    int blk = blockIdx.x;
    int split = blk >> 9;      // 0: c 0..31, 1: c 32..63
    int rb = blk & 511;
    int b = rb >> 6;
    int h0 = (rb & 63) * 2;
    int tid = threadIdx.x;
    int r = tid >> 7;
    int wcol = tid & 127;
    int h = h0 + r;

    float acc[OC];
#pragma unroll
    for (int oc = 0; oc < OC; ++oc) acc[oc] = (split == 0) ? ob[oc] : 0.0f;

    const float* xb = x + (size_t)b * (C * HW) + (size_t)split * 32 * HW;

    float pre[2 * CSTEP];
    auto load_step = [&](int c0) {
#pragma unroll
        for (int i = 0; i < 2 * CSTEP; ++i) {
            int idx = i * 256 + tid;
            int cc = idx >> 9;
            int rr = (idx >> 7) & 3;
            int col = idx & 127;
            int y = h0 - 1 + rr;
            pre[i] = ((unsigned)y < H) ? xb[(size_t)(c0 + cc) * HW + y * W + col] : 0.0f;
        }
    };
    load_step(0);

    for (int c0 = 0; c0 < 32; c0 += CSTEP) {
        __syncthreads();  // WAR: previous compute's reads complete
#pragma unroll
        for (int i = 0; i < 2 * CSTEP; ++i) xs[i * 256 + tid] = pre[i];
        __syncthreads();
        if (c0 + CSTEP < 32) load_step(c0 + CSTEP);  // overlap with compute
#pragma unroll
        for (int cc = 0; cc < CSTEP; ++cc) {
            const float* wc = owT + (size_t)(split * 32 + c0 + cc) * (OC * KK);
            float xv[9];
#pragma unroll
            for (int dr = 0; dr < 3; ++dr)
#pragma unroll
                for (int dw = 0; dw < 3; ++dw) {
                    int col = wcol - 1 + dw;
                    xv[dr * 3 + dw] =
                        ((unsigned)col < W) ? xs[(cc * 4 + r + dr) * 128 + col] : 0.0f;
                }
#pragma unroll
            for (int oc = 0; oc < OC; ++oc) {
#pragma unroll
                for (int k = 0; k < KK; ++k)
                    acc[oc] = fmaf(wc[oc * KK + k], xv[k], acc[oc]);
            }
        }
    }
#pragma unroll
    for (int oc = 0; oc < OC; ++oc)
        omp[(((size_t)(split * B + b) * OC + oc) * H + h) * W + wcol] = acc[oc];
}

// ---------------------------------------------------------------------------
// Kernel 4: fused deformable sampling + MFMA einsum. 16 pixels / block.
//  A0: thread t<144 computes meta for pair (k=t>>4, p=t&15):
//      4 mask-premultiplied bilinear weights (zeroed when corner OOB) +
//      4 clamped byte offsets into the bf16 NHWC image.
//  A1: wave wv, lane=c: pixels [wv*4,wv*4+4), 9 taps; 4 gathers + 4 FMA +
//      bf16 pack -> swizzled LDS samp[pix][K].
//  B : wave wv owns o-rows [wv*16,wv*16+16); 18 x mfma_f32_16x16x32_bf16,
//      afrag streamed from L2-resident wB.
// ---------------------------------------------------------------------------
__global__ __launch_bounds__(256) void k_main(const ushort* __restrict__ xTb,
                                              const float* __restrict__ omp,
                                              const ushort* __restrict__ wB,
                                              const float* __restrict__ bias,
                                              float* __restrict__ out) {
    __shared__ __align__(16) char smem[NPIX * LDSROW];  // 18432 B
    __shared__ float4 meta_w[NPAIR];                    // 2304 B
    __shared__ int4 meta_o[NPAIR];                      // 2304 B

    int tid = threadIdx.x;
    int lane = tid & 63;
    int wv = tid >> 6;
    int pb = blockIdx.x * NPIX;
    int b = pb >> 14;
    int rem = pb & (HW - 1);
    int h = rem >> 7;
    int w0 = rem & (W - 1);

    // ---- Phase A0: per-pair metadata ----
    if (tid < NPAIR) {
        int k = tid >> 4;
        int p = tid & 15;
        int dh = k / 3 - 1;
        int dw = k % 3 - 1;
        const float* o0 = omp + ((size_t)b * OC) * HW + h * W + w0 + p;
        const float* o1 = o0 + (size_t)B * OC * HW;
        float offx = o0[(size_t)k * HW] + o1[(size_t)k * HW];
        float offy = o0[(size_t)(KK + k) * HW] + o1[(size_t)(KK + k) * HW];
        float mlog = o0[(size_t)(2 * KK + k) * HW] + o1[(size_t)(2 * KK + k) * HW];
        float mask = 1.0f / (1.0f + __expf(-mlog));
        float gx = (float)(w0 + p + dw) + offx;
        float gy = (float)(h + dh) + offy;
        float x0f = floorf(gx), y0f = floorf(gy);
        int x0 = (int)x0f, y0 = (int)y0f;
        int x1 = x0 + 1, y1 = y0 + 1;
        float wx1 = gx - x0f, wy1 = gy - y0f;
        float wx0 = 1.0f - wx1, wy0 = 1.0f - wy1;
        bool vy0 = (unsigned)y0 < H, vy1 = (unsigned)y1 < H;
        bool vx0 = (unsigned)x0 < W, vx1 = (unsigned)x1 < W;
        float w00 = (vy0 && vx0) ? wy0 * wx0 * mask : 0.0f;
        float w01 = (vy0 && vx1) ? wy0 * wx1 * mask : 0.0f;
        float w10 = (vy1 && vx0) ? wy1 * wx0 * mask : 0.0f;
        float w11 = (vy1 && vx1) ? wy1 * wx1 * mask : 0.0f;
        int x0c = min(max(x0, 0), W - 1), x1c = min(max(x1, 0), W - 1);
        int y0c = min(max(y0, 0), H - 1), y1c = min(max(y1, 0), H - 1);
        meta_w[tid] = make_float4(w00, w01, w10, w11);
        // byte offsets into bf16 NHWC image: ((y*W+x)*64 ch)*2B
        meta_o[tid] = make_int4((y0c * W + x0c) * (C * 2), (y0c * W + x1c) * (C * 2),
                                (y1c * W + x0c) * (C * 2), (y1c * W + x1c) * (C * 2));
    }
    __syncthreads();

    // ---- Phase A1: gather + blend + pack ----
    const char* xbase = (const char*)(xTb + (size_t)b * (HW * C));
#pragma unroll
    for (int k = 0; k < KK; ++k) {
#pragma unroll
        for (int pp = 0; pp < 4; ++pp) {
            int p = wv * 4 + pp;
            int pair = k * 16 + p;
            float4 mw = meta_w[pair];
            int4 mo = meta_o[pair];
            float g00 = bf2f(*(const ushort*)(xbase + mo.x + lane * 2));
            float g01 = bf2f(*(const ushort*)(xbase + mo.y + lane * 2));
            float g10 = bf2f(*(const ushort*)(xbase + mo.z + lane * 2));
            float g11 = bf2f(*(const ushort*)(xbase + mo.w + lane * 2));
            float v = g00 * mw.x + g01 * mw.y + g10 * mw.z + g11 * mw.w;
            int byte = (p * LDSROW + (k * 64 + lane) * 2) ^ ((p & 7) << 4);
            *(ushort*)(smem + byte) = f2bf(v);
        }
    }
    __syncthreads();

    // ---- Phase B: MFMA ----
    f32x4 acc;
#pragma unroll
    for (int j = 0; j < 4; ++j) acc[j] = bias[wv * 16 + (lane >> 4) * 4 + j];

    int pix = lane & 15;
    const ushort* wrow = wB + (size_t)(wv * 16 + pix) * KDIM + (lane >> 4) * 8;
#pragma unroll
    for (int s = 0; s < 18; ++s) {
        int kbyte = s * 64 + (lane >> 4) * 16;
        int byte = (pix * LDSROW + kbyte) ^ ((pix & 7) << 4);
        s16x8 bfrag = *(const s16x8*)(smem + byte);
        s16x8 afrag = *(const s16x8*)(wrow + s * 32);
        acc = __builtin_amdgcn_mfma_f32_16x16x32_bf16(afrag, bfrag, acc, 0, 0, 0);
    }

    float* obase = out + ((size_t)(b * COUT + wv * 16 + (lane >> 4) * 4) * HW) + h * W + w0;
#pragma unroll
    for (int j = 0; j < 4; ++j) obase[(size_t)j * HW + pix] = acc[j];
}

// ---------------------------------------------------------------------------
extern "C" void kernel_launch(void* const* d_in, const int* in_sizes, int n_in,
                              void* d_out, int out_size, void* d_ws, size_t ws_size,
                              hipStream_t stream) {
    const float* x = (const float*)d_in[0];
    const float* ow = (const float*)d_in[1];
    const float* ob = (const float*)d_in[2];
    const float* w = (const float*)d_in[3];
    const float* bias = (const float*)d_in[4];
    float* out = (float*)d_out;

    float* omp = (float*)d_ws;                          // 2*B*27*HW  = 7077888 f
    float* owT = omp + (size_t)2 * B * OC * HW;         // 15552 f
    ushort* xTb = (ushort*)(owT + (size_t)OC * C * KK); // B*HW*C ushort
    ushort* wB = xTb + (size_t)B * HW * C;              // 36864 ushort
    // total ~45.4 MB

    hipLaunchKernelGGL(k_transpose_x, dim3(B * 256), dim3(256), 0, stream, x, xTb);
    hipLaunchKernelGGL(k_prep_w, dim3((COUT * KDIM + 255) / 256), dim3(256), 0,
                       stream, w, wB);
    hipLaunchKernelGGL(k_transpose_ow, dim3((OC * C * KK + 255) / 256), dim3(256), 0,
                       stream, ow, owT);
    hipLaunchKernelGGL(k_om, dim3(B * H), dim3(256), 0, stream, x, owT, ob, omp);
    hipLaunchKernelGGL(k_main, dim3(B * HW / NPIX), dim3(256), 0, stream,
                       xTb, omp, wB, bias, out);
}

// Round 5
// 173.216 us; speedup vs baseline: 7.3460x; 1.5645x over previous
//
#include <hip/hip_runtime.h>

#define B 8
#define C 64
#define H 128
#define W 128
#define HW (H * W)
#define OC 27
#define KK 9
#define COUT 64
#define KDIM 576           // 9*64
#define LDSROW 1152        // bytes per pixel row (576 * 2B)
#define NPIX 16            // pixels per k_main workgroup
#define NPAIR (NPIX * KK)  // 144

typedef __attribute__((ext_vector_type(8))) short s16x8;
typedef __attribute__((ext_vector_type(4))) float f32x4;

__device__ inline ushort f2bf(float f) {
    union { float f; unsigned u; } uv;
    uv.f = f;
    unsigned r = uv.u + 0x7FFF + ((uv.u >> 16) & 1);
    return (ushort)(r >> 16);
}
__device__ inline float bf2f(ushort u) {
    return __uint_as_float((unsigned)u << 16);
}

// ---------------------------------------------------------------------------
// Kernel 1: transpose x (NCHW fp32) -> xTb (NHWC bf16).
// ---------------------------------------------------------------------------
__global__ __launch_bounds__(256) void k_transpose_x(const float* __restrict__ x,
                                                     ushort* __restrict__ xTb) {
    __shared__ float lds[64][65];
    int b = blockIdx.x >> 8;
    int tile = blockIdx.x & 255;
    int hw0 = tile * 64;
    int lane = threadIdx.x & 63;
    int cg = threadIdx.x >> 6;
#pragma unroll
    for (int r = 0; r < 16; ++r) {
        int c = cg * 16 + r;
        lds[c][lane] = x[(size_t)(b * C + c) * HW + hw0 + lane];
    }
    __syncthreads();
#pragma unroll
    for (int r = 0; r < 16; ++r) {
        int hwl = cg * 16 + r;
        xTb[(size_t)(b * HW + hw0 + hwl) * C + lane] = f2bf(lds[lane][hwl]);
    }
}

// ---------------------------------------------------------------------------
// Kernel 2: repack w (Cout,C,3,3) fp32 -> wB[o][K] bf16, K = tap*64 + c.
// ---------------------------------------------------------------------------
__global__ __launch_bounds__(256) void k_prep_w(const float* __restrict__ w,
                                                ushort* __restrict__ wB) {
    int idx = blockIdx.x * 256 + threadIdx.x;
    if (idx >= COUT * KDIM) return;
    int o = idx / KDIM;
    int Kx = idx % KDIM;
    int k = Kx >> 6;
    int c = Kx & 63;
    wB[idx] = f2bf(w[(size_t)(o * C + c) * KK + k]);
}

// ---------------------------------------------------------------------------
// Kernel 2b: repack ow (27,C,3,3) fp32 -> awB[32][576] bf16 (rows 27..31 = 0),
// K = tap*64 + c  (must match k_om's B-fragment K indexing).
// ---------------------------------------------------------------------------
__global__ __launch_bounds__(256) void k_prep_aw(const float* __restrict__ ow,
                                                 ushort* __restrict__ awB) {
    int idx = blockIdx.x * 256 + threadIdx.x;  // o*576 + K
    if (idx >= 32 * KDIM) return;
    int o = idx / KDIM;
    int Kx = idx % KDIM;
    int tap = Kx >> 6;
    int c = Kx & 63;
    float v = (o < OC) ? ow[((size_t)o * C + c) * KK + tap] : 0.0f;
    awB[idx] = f2bf(v);
}

// ---------------------------------------------------------------------------
// Kernel 3 (MFMA rewrite): offset/mask conv as im2col GEMM.
// Block = 64 consecutive pixels of one row; 4 waves x 16 pixels.
// Stage xwin: 3 rows x 66 cols x 64ch bf16 in LDS (XOR-swizzled).
// Per wave: 18 K-steps x 2 M-blocks of mfma_f32_16x16x32_bf16;
//   A (weights) streamed from L2-resident awB; bias added at C-write.
// om[b][27][H][W] fp32.
// ---------------------------------------------------------------------------
__global__ __launch_bounds__(256) void k_om(const ushort* __restrict__ xTb,
                                            const ushort* __restrict__ awB,
                                            const float* __restrict__ ob,
                                            float* __restrict__ om) {
    __shared__ __align__(16) char xwin[3 * 66 * 128];  // 25344 B
    int tid = threadIdx.x;
    int lane = tid & 63;
    int wv = tid >> 6;
    int blk = blockIdx.x;  // b*256 + h*2 + (w0/64)
    int b = blk >> 8;
    int h = (blk >> 1) & 127;
    int w0 = (blk & 1) * 64;

    // ---- stage 3x66x64ch bf16, zero-filled at borders ----
    const ushort* xb = xTb + (size_t)b * (HW * C);
    int ch2 = tid & 31;  // 2 channels (4B) per lane
#pragma unroll
    for (int it = 0; it < 25; ++it) {
        int pi = it * 8 + (tid >> 5);  // (row,col) pair index, 198 total
        if (pi < 198) {
            int row = pi / 66;
            int col = pi - row * 66;
            int y = h - 1 + row;
            int xc = w0 - 1 + col;
            unsigned v = 0;
            if ((unsigned)y < H && (unsigned)xc < W)
                v = *(const unsigned*)(xb + ((size_t)(y * W + xc) << 6) + ch2 * 2);
            int byte = (pi * 128 + ch2 * 4) ^ ((col & 7) << 4);
            *(unsigned*)(xwin + byte) = v;
        }
    }
    __syncthreads();

    // ---- MFMA: M=32 (oc, rows 27..31 dead), N=16 pix/wave, K=576 ----
    f32x4 acc0 = {0.f, 0.f, 0.f, 0.f};
    f32x4 acc1 = {0.f, 0.f, 0.f, 0.f};
    int pixl = lane & 15;
    int q = lane >> 4;
    int base_col = wv * 16 + pixl;
    const ushort* a0 = awB + (size_t)pixl * KDIM + q * 8;
    const ushort* a1 = awB + (size_t)(16 + pixl) * KDIM + q * 8;
#pragma unroll
    for (int s = 0; s < 18; ++s) {
        int tap = s >> 1;           // lane-uniform: K-run stays inside one tap
        int row = tap / 3;
        int cs = tap - row * 3;
        int col = base_col + cs;
        int c0b = ((s & 1) * 32 + q * 8) * 2;  // channel byte offset within tap
        int byte = (((row * 66 + col) << 7) + c0b) ^ ((col & 7) << 4);
        s16x8 bfrag = *(const s16x8*)(xwin + byte);
        s16x8 af0 = *(const s16x8*)(a0 + s * 32);
        s16x8 af1 = *(const s16x8*)(a1 + s * 32);
        acc0 = __builtin_amdgcn_mfma_f32_16x16x32_bf16(af0, bfrag, acc0, 0, 0, 0);
        acc1 = __builtin_amdgcn_mfma_f32_16x16x32_bf16(af1, bfrag, acc1, 0, 0, 0);
    }

    // ---- C-write: oc = Mblk*16 + q*4 + j, pix = lane&15 ----
    int pix = wv * 16 + pixl;
#pragma unroll
    for (int j = 0; j < 4; ++j) {
        int oc = q * 4 + j;
        om[(((size_t)b * OC + oc) * H + h) * W + w0 + pix] = acc0[j] + ob[oc];
        int oc1 = 16 + q * 4 + j;
        if (oc1 < OC)
            om[(((size_t)b * OC + oc1) * H + h) * W + w0 + pix] = acc1[j] + ob[oc1];
    }
}

// ---------------------------------------------------------------------------
// Kernel 4: fused deformable sampling + MFMA einsum (A0 reads fused om now).
// ---------------------------------------------------------------------------
__global__ __launch_bounds__(256) void k_main(const ushort* __restrict__ xTb,
                                              const float* __restrict__ om,
                                              const ushort* __restrict__ wB,
                                              const float* __restrict__ bias,
                                              float* __restrict__ out) {
    __shared__ __align__(16) char smem[NPIX * LDSROW];  // 18432 B
    __shared__ float4 meta_w[NPAIR];
    __shared__ int4 meta_o[NPAIR];

    int tid = threadIdx.x;
    int lane = tid & 63;
    int wv = tid >> 6;
    int pb = blockIdx.x * NPIX;
    int b = pb >> 14;
    int rem = pb & (HW - 1);
    int h = rem >> 7;
    int w0 = rem & (W - 1);

    // ---- Phase A0: per-(pixel,tap) metadata ----
    if (tid < NPAIR) {
        int k = tid >> 4;
        int p = tid & 15;
        int dh = k / 3 - 1;
        int dw = k % 3 - 1;
        const float* o0 = om + ((size_t)b * OC) * HW + h * W + w0 + p;
        float offx = o0[(size_t)k * HW];
        float offy = o0[(size_t)(KK + k) * HW];
        float mlog = o0[(size_t)(2 * KK + k) * HW];
        float mask = 1.0f / (1.0f + __expf(-mlog));
        float gx = (float)(w0 + p + dw) + offx;
        float gy = (float)(h + dh) + offy;
        float x0f = floorf(gx), y0f = floorf(gy);
        int x0 = (int)x0f, y0 = (int)y0f;
        int x1 = x0 + 1, y1 = y0 + 1;
        float wx1 = gx - x0f, wy1 = gy - y0f;
        float wx0 = 1.0f - wx1, wy0 = 1.0f - wy1;
        bool vy0 = (unsigned)y0 < H, vy1 = (unsigned)y1 < H;
        bool vx0 = (unsigned)x0 < W, vx1 = (unsigned)x1 < W;
        float w00 = (vy0 && vx0) ? wy0 * wx0 * mask : 0.0f;
        float w01 = (vy0 && vx1) ? wy0 * wx1 * mask : 0.0f;
        float w10 = (vy1 && vx0) ? wy1 * wx0 * mask : 0.0f;
        float w11 = (vy1 && vx1) ? wy1 * wx1 * mask : 0.0f;
        int x0c = min(max(x0, 0), W - 1), x1c = min(max(x1, 0), W - 1);
        int y0c = min(max(y0, 0), H - 1), y1c = min(max(y1, 0), H - 1);
        meta_w[tid] = make_float4(w00, w01, w10, w11);
        meta_o[tid] = make_int4((y0c * W + x0c) * (C * 2), (y0c * W + x1c) * (C * 2),
                                (y1c * W + x0c) * (C * 2), (y1c * W + x1c) * (C * 2));
    }
    __syncthreads();

    // ---- Phase A1: gather + blend + pack ----
    const char* xbase = (const char*)(xTb + (size_t)b * (HW * C));
#pragma unroll
    for (int k = 0; k < KK; ++k) {
#pragma unroll
        for (int pp = 0; pp < 4; ++pp) {
            int p = wv * 4 + pp;
            int pair = k * 16 + p;
            float4 mw = meta_w[pair];
            int4 mo = meta_o[pair];
            float g00 = bf2f(*(const ushort*)(xbase + mo.x + lane * 2));
            float g01 = bf2f(*(const ushort*)(xbase + mo.y + lane * 2));
            float g10 = bf2f(*(const ushort*)(xbase + mo.z + lane * 2));
            float g11 = bf2f(*(const ushort*)(xbase + mo.w + lane * 2));
            float v = g00 * mw.x + g01 * mw.y + g10 * mw.z + g11 * mw.w;
            int byte = (p * LDSROW + (k * 64 + lane) * 2) ^ ((p & 7) << 4);
            *(ushort*)(smem + byte) = f2bf(v);
        }
    }
    __syncthreads();

    // ---- Phase B: MFMA ----
    f32x4 acc;
#pragma unroll
    for (int j = 0; j < 4; ++j) acc[j] = bias[wv * 16 + (lane >> 4) * 4 + j];

    int pix = lane & 15;
    const ushort* wrow = wB + (size_t)(wv * 16 + pix) * KDIM + (lane >> 4) * 8;
#pragma unroll
    for (int s = 0; s < 18; ++s) {
        int kbyte = s * 64 + (lane >> 4) * 16;
        int byte = (pix * LDSROW + kbyte) ^ ((pix & 7) << 4);
        s16x8 bfrag = *(const s16x8*)(smem + byte);
        s16x8 afrag = *(const s16x8*)(wrow + s * 32);
        acc = __builtin_amdgcn_mfma_f32_16x16x32_bf16(afrag, bfrag, acc, 0, 0, 0);
    }

    float* obase = out + ((size_t)(b * COUT + wv * 16 + (lane >> 4) * 4) * HW) + h * W + w0;
#pragma unroll
    for (int j = 0; j < 4; ++j) obase[(size_t)j * HW + pix] = acc[j];
}

// ---------------------------------------------------------------------------
extern "C" void kernel_launch(void* const* d_in, const int* in_sizes, int n_in,
                              void* d_out, int out_size, void* d_ws, size_t ws_size,
                              hipStream_t stream) {
    const float* x = (const float*)d_in[0];
    const float* ow = (const float*)d_in[1];
    const float* ob = (const float*)d_in[2];
    const float* w = (const float*)d_in[3];
    const float* bias = (const float*)d_in[4];
    float* out = (float*)d_out;

    float* om = (float*)d_ws;                           // B*27*HW = 3538944 f
    ushort* xTb = (ushort*)(om + (size_t)B * OC * HW);  // B*HW*C ushort
    ushort* wB = xTb + (size_t)B * HW * C;              // 36864 ushort
    ushort* awB = wB + (size_t)COUT * KDIM;             // 18432 ushort
    // total ~31.1 MB

    hipLaunchKernelGGL(k_transpose_x, dim3(B * 256), dim3(256), 0, stream, x, xTb);
    hipLaunchKernelGGL(k_prep_w, dim3((COUT * KDIM + 255) / 256), dim3(256), 0,
                       stream, w, wB);
    hipLaunchKernelGGL(k_prep_aw, dim3((32 * KDIM + 255) / 256), dim3(256), 0,
                       stream, ow, awB);
    hipLaunchKernelGGL(k_om, dim3(B * H * 2), dim3(256), 0, stream, xTb, awB, ob, om);
    hipLaunchKernelGGL(k_main, dim3(B * HW / NPIX), dim3(256), 0, stream,
                       xTb, om, wB, bias, out);
}

// Round 6
// 172.042 us; speedup vs baseline: 7.3961x; 1.0068x over previous
//
#include <hip/hip_runtime.h>

#define B 8
#define C 64
#define H 128
#define W 128
#define HW (H * W)
#define OC 27
#define KK 9
#define COUT 64
#define KDIM 576           // 9*64
#define LDSROW 1152        // bytes per pixel row (576 * 2B)
#define NPIX 16            // pixels per k_main workgroup
#define NPAIR (NPIX * KK)  // 144

typedef __attribute__((ext_vector_type(8))) short s16x8;
typedef __attribute__((ext_vector_type(4))) float f32x4;

__device__ inline ushort f2bf(float f) {
    union { float f; unsigned u; } uv;
    uv.f = f;
    unsigned r = uv.u + 0x7FFF + ((uv.u >> 16) & 1);
    return (ushort)(r >> 16);
}
__device__ inline float bf2f(ushort u) {
    return __uint_as_float((unsigned)u << 16);
}

// ---------------------------------------------------------------------------
// Kernel 1: transpose x (NCHW fp32) -> xTb (NHWC bf16).
// ---------------------------------------------------------------------------
__global__ __launch_bounds__(256) void k_transpose_x(const float* __restrict__ x,
                                                     ushort* __restrict__ xTb) {
    __shared__ float lds[64][65];
    int b = blockIdx.x >> 8;
    int tile = blockIdx.x & 255;
    int hw0 = tile * 64;
    int lane = threadIdx.x & 63;
    int cg = threadIdx.x >> 6;
#pragma unroll
    for (int r = 0; r < 16; ++r) {
        int c = cg * 16 + r;
        lds[c][lane] = x[(size_t)(b * C + c) * HW + hw0 + lane];
    }
    __syncthreads();
#pragma unroll
    for (int r = 0; r < 16; ++r) {
        int hwl = cg * 16 + r;
        xTb[(size_t)(b * HW + hw0 + hwl) * C + lane] = f2bf(lds[lane][hwl]);
    }
}

// ---------------------------------------------------------------------------
// Kernel 2: repack w (Cout,C,3,3) fp32 -> wB[o][K] bf16, K = tap*64 + c.
// ---------------------------------------------------------------------------
__global__ __launch_bounds__(256) void k_prep_w(const float* __restrict__ w,
                                                ushort* __restrict__ wB) {
    int idx = blockIdx.x * 256 + threadIdx.x;
    if (idx >= COUT * KDIM) return;
    int o = idx / KDIM;
    int Kx = idx % KDIM;
    int k = Kx >> 6;
    int c = Kx & 63;
    wB[idx] = f2bf(w[(size_t)(o * C + c) * KK + k]);
}

// ---------------------------------------------------------------------------
// Kernel 2b: repack ow (27,C,3,3) fp32 -> awB[32][576] bf16 (rows 27..31 = 0),
// K = tap*64 + c  (must match k_om's B-fragment K indexing).
// ---------------------------------------------------------------------------
__global__ __launch_bounds__(256) void k_prep_aw(const float* __restrict__ ow,
                                                 ushort* __restrict__ awB) {
    int idx = blockIdx.x * 256 + threadIdx.x;  // o*576 + K
    if (idx >= 32 * KDIM) return;
    int o = idx / KDIM;
    int Kx = idx % KDIM;
    int tap = Kx >> 6;
    int c = Kx & 63;
    float v = (o < OC) ? ow[((size_t)o * C + c) * KK + tap] : 0.0f;
    awB[idx] = f2bf(v);
}

// ---------------------------------------------------------------------------
// Kernel 3: offset/mask conv as im2col GEMM (unchanged from R4).
// ---------------------------------------------------------------------------
__global__ __launch_bounds__(256) void k_om(const ushort* __restrict__ xTb,
                                            const ushort* __restrict__ awB,
                                            const float* __restrict__ ob,
                                            float* __restrict__ om) {
    __shared__ __align__(16) char xwin[3 * 66 * 128];  // 25344 B
    int tid = threadIdx.x;
    int lane = tid & 63;
    int wv = tid >> 6;
    int blk = blockIdx.x;  // b*256 + h*2 + (w0/64)
    int b = blk >> 8;
    int h = (blk >> 1) & 127;
    int w0 = (blk & 1) * 64;

    const ushort* xb = xTb + (size_t)b * (HW * C);
    int ch2 = tid & 31;
#pragma unroll
    for (int it = 0; it < 25; ++it) {
        int pi = it * 8 + (tid >> 5);
        if (pi < 198) {
            int row = pi / 66;
            int col = pi - row * 66;
            int y = h - 1 + row;
            int xc = w0 - 1 + col;
            unsigned v = 0;
            if ((unsigned)y < H && (unsigned)xc < W)
                v = *(const unsigned*)(xb + ((size_t)(y * W + xc) << 6) + ch2 * 2);
            int byte = (pi * 128 + ch2 * 4) ^ ((col & 7) << 4);
            *(unsigned*)(xwin + byte) = v;
        }
    }
    __syncthreads();

    f32x4 acc0 = {0.f, 0.f, 0.f, 0.f};
    f32x4 acc1 = {0.f, 0.f, 0.f, 0.f};
    int pixl = lane & 15;
    int q = lane >> 4;
    int base_col = wv * 16 + pixl;
    const ushort* a0 = awB + (size_t)pixl * KDIM + q * 8;
    const ushort* a1 = awB + (size_t)(16 + pixl) * KDIM + q * 8;
#pragma unroll
    for (int s = 0; s < 18; ++s) {
        int tap = s >> 1;
        int row = tap / 3;
        int cs = tap - row * 3;
        int col = base_col + cs;
        int c0b = ((s & 1) * 32 + q * 8) * 2;
        int byte = (((row * 66 + col) << 7) + c0b) ^ ((col & 7) << 4);
        s16x8 bfrag = *(const s16x8*)(xwin + byte);
        s16x8 af0 = *(const s16x8*)(a0 + s * 32);
        s16x8 af1 = *(const s16x8*)(a1 + s * 32);
        acc0 = __builtin_amdgcn_mfma_f32_16x16x32_bf16(af0, bfrag, acc0, 0, 0, 0);
        acc1 = __builtin_amdgcn_mfma_f32_16x16x32_bf16(af1, bfrag, acc1, 0, 0, 0);
    }

    int pix = wv * 16 + pixl;
#pragma unroll
    for (int j = 0; j < 4; ++j) {
        int oc = q * 4 + j;
        om[(((size_t)b * OC + oc) * H + h) * W + w0 + pix] = acc0[j] + ob[oc];
        int oc1 = 16 + q * 4 + j;
        if (oc1 < OC)
            om[(((size_t)b * OC + oc1) * H + h) * W + w0 + pix] = acc1[j] + ob[oc1];
    }
}

// ---------------------------------------------------------------------------
// Kernel 4: fused deformable sampling + MFMA einsum.
//  A0: per (pixel,tap): 2 ROW-BASE byte offsets (each row covers 2 adjacent
//      column slots = 256B contiguous) + 4 slot weights with boundary
//      column-permutation and mask folded in.
//  A1: lane=c: per pair, 2 scalar bases (readfirstlane) -> 4 ushort gathers
//      (saddr + shared voffset, offset:128 imm), blend, pack, ds_write with
//      tap-immediate offset.
//  B : 18 x mfma_f32_16x16x32_bf16 per wave.
// ---------------------------------------------------------------------------
__global__ __launch_bounds__(256, 6) void k_main(const ushort* __restrict__ xTb,
                                                 const float* __restrict__ om,
                                                 const ushort* __restrict__ wB,
                                                 const float* __restrict__ bias,
                                                 float* __restrict__ out) {
    __shared__ __align__(16) char smem[NPIX * LDSROW];  // 18432 B
    __shared__ float4 meta_w[NPAIR];                    // 2304 B
    __shared__ int2 meta_o[NPAIR];                      // 1152 B

    int tid = threadIdx.x;
    int lane = tid & 63;
    int wv = tid >> 6;
    int pb = blockIdx.x * NPIX;
    int b = pb >> 14;
    int rem = pb & (HW - 1);
    int h = rem >> 7;
    int w0 = rem & (W - 1);

    // ---- Phase A0: per-(pixel,tap) slot metadata ----
    if (tid < NPAIR) {
        int k = tid >> 4;
        int p = tid & 15;
        int dh = k / 3 - 1;
        int dw = k % 3 - 1;
        const float* o0 = om + ((size_t)b * OC) * HW + h * W + w0 + p;
        float offx = o0[(size_t)k * HW];
        float offy = o0[(size_t)(KK + k) * HW];
        float mlog = o0[(size_t)(2 * KK + k) * HW];
        float mask = 1.0f / (1.0f + __expf(-mlog));
        float gx = (float)(w0 + p + dw) + offx;
        float gy = (float)(h + dh) + offy;
        float x0f = floorf(gx), y0f = floorf(gy);
        int x0 = (int)x0f, y0 = (int)y0f;
        int x1 = x0 + 1, y1 = y0 + 1;
        float wx1 = gx - x0f, wy1 = gy - y0f;
        float wx0 = 1.0f - wx1, wy0 = 1.0f - wy1;
        // row weights (validity folded), row bases clamped
        float rw0 = ((unsigned)y0 < H) ? wy0 * mask : 0.0f;
        float rw1 = ((unsigned)y1 < H) ? wy1 * mask : 0.0f;
        int y0c = min(max(y0, 0), H - 1), y1c = min(max(y1, 0), H - 1);
        // column slots: base = clamp(x0, 0, W-2); permute weights into slots
        int colbase = min(max(x0, 0), W - 2);
        float cw0 = 0.0f, cw1 = 0.0f;
        if ((unsigned)x0 < W) { if (x0 == colbase) cw0 += wx0; else cw1 += wx0; }
        if ((unsigned)x1 < W) { if (x1 == colbase) cw0 += wx1; else cw1 += wx1; }
        meta_w[tid] = make_float4(rw0 * cw0, rw0 * cw1, rw1 * cw0, rw1 * cw1);
        meta_o[tid] = make_int2((y0c * W + colbase) * (C * 2),
                                (y1c * W + colbase) * (C * 2));
    }
    __syncthreads();

    // ---- Phase A1: gather + blend + pack ----
    const char* xbase = (const char*)(xTb + (size_t)b * (HW * C));
#pragma unroll
    for (int pp = 0; pp < 4; ++pp) {
        int p = wv * 4 + pp;
        int vlds = p * LDSROW + ((lane * 2) ^ ((p & 7) << 4));
#pragma unroll
        for (int k = 0; k < KK; ++k) {
            int pair = k * 16 + p;
            float4 mw = meta_w[pair];
            int2 mo = meta_o[pair];
            const ushort* r0 =
                (const ushort*)(xbase + __builtin_amdgcn_readfirstlane(mo.x));
            const ushort* r1 =
                (const ushort*)(xbase + __builtin_amdgcn_readfirstlane(mo.y));
            float g00 = bf2f(r0[lane]);
            float g01 = bf2f(r0[64 + lane]);
            float g10 = bf2f(r1[lane]);
            float g11 = bf2f(r1[64 + lane]);
            float v = g00 * mw.x + g01 * mw.y + g10 * mw.z + g11 * mw.w;
            *(ushort*)(smem + vlds + k * 128) = f2bf(v);
        }
    }
    __syncthreads();

    // ---- Phase B: MFMA ----
    f32x4 acc;
#pragma unroll
    for (int j = 0; j < 4; ++j) acc[j] = bias[wv * 16 + (lane >> 4) * 4 + j];

    int pix = lane & 15;
    const ushort* wrow = wB + (size_t)(wv * 16 + pix) * KDIM + (lane >> 4) * 8;
#pragma unroll
    for (int s = 0; s < 18; ++s) {
        int kbyte = s * 64 + (lane >> 4) * 16;
        int byte = (pix * LDSROW + kbyte) ^ ((pix & 7) << 4);
        s16x8 bfrag = *(const s16x8*)(smem + byte);
        s16x8 afrag = *(const s16x8*)(wrow + s * 32);
        acc = __builtin_amdgcn_mfma_f32_16x16x32_bf16(afrag, bfrag, acc, 0, 0, 0);
    }

    float* obase = out + ((size_t)(b * COUT + wv * 16 + (lane >> 4) * 4) * HW) + h * W + w0;
#pragma unroll
    for (int j = 0; j < 4; ++j) obase[(size_t)j * HW + pix] = acc[j];
}

// ---------------------------------------------------------------------------
extern "C" void kernel_launch(void* const* d_in, const int* in_sizes, int n_in,
                              void* d_out, int out_size, void* d_ws, size_t ws_size,
                              hipStream_t stream) {
    const float* x = (const float*)d_in[0];
    const float* ow = (const float*)d_in[1];
    const float* ob = (const float*)d_in[2];
    const float* w = (const float*)d_in[3];
    const float* bias = (const float*)d_in[4];
    float* out = (float*)d_out;

    float* om = (float*)d_ws;                           // B*27*HW = 3538944 f
    ushort* xTb = (ushort*)(om + (size_t)B * OC * HW);  // B*HW*C ushort
    ushort* wB = xTb + (size_t)B * HW * C;              // 36864 ushort
    ushort* awB = wB + (size_t)COUT * KDIM;             // 18432 ushort
    // total ~31.1 MB

    hipLaunchKernelGGL(k_transpose_x, dim3(B * 256), dim3(256), 0, stream, x, xTb);
    hipLaunchKernelGGL(k_prep_w, dim3((COUT * KDIM + 255) / 256), dim3(256), 0,
                       stream, w, wB);
    hipLaunchKernelGGL(k_prep_aw, dim3((32 * KDIM + 255) / 256), dim3(256), 0,
                       stream, ow, awB);
    hipLaunchKernelGGL(k_om, dim3(B * H * 2), dim3(256), 0, stream, xTb, awB, ob, om);
    hipLaunchKernelGGL(k_main, dim3(B * HW / NPIX), dim3(256), 0, stream,
                       xTb, om, wB, bias, out);
}

// Round 7
// 170.357 us; speedup vs baseline: 7.4692x; 1.0099x over previous
//
#include <hip/hip_runtime.h>

#define B 8
#define C 64
#define H 128
#define W 128
#define HW (H * W)
#define OC 27
#define KK 9
#define COUT 64
#define KDIM 576           // 9*64
#define LDSROW 1152        // bytes per pixel row (576 * 2B)
#define NPIX 16            // pixels per k_main workgroup
#define NPAIR (NPIX * KK)  // 144

typedef __attribute__((ext_vector_type(8))) short s16x8;
typedef __attribute__((ext_vector_type(4))) float f32x4;

__device__ inline ushort f2bf(float f) {
    union { float f; unsigned u; } uv;
    uv.f = f;
    unsigned r = uv.u + 0x7FFF + ((uv.u >> 16) & 1);
    return (ushort)(r >> 16);
}
__device__ inline float bf2f(ushort u) {
    return __uint_as_float((unsigned)u << 16);
}

// ---------------------------------------------------------------------------
// Kernel 1: transpose x (NCHW fp32) -> xTb (NHWC bf16).
// ---------------------------------------------------------------------------
__global__ __launch_bounds__(256) void k_transpose_x(const float* __restrict__ x,
                                                     ushort* __restrict__ xTb) {
    __shared__ float lds[64][65];
    int b = blockIdx.x >> 8;
    int tile = blockIdx.x & 255;
    int hw0 = tile * 64;
    int lane = threadIdx.x & 63;
    int cg = threadIdx.x >> 6;
#pragma unroll
    for (int r = 0; r < 16; ++r) {
        int c = cg * 16 + r;
        lds[c][lane] = x[(size_t)(b * C + c) * HW + hw0 + lane];
    }
    __syncthreads();
#pragma unroll
    for (int r = 0; r < 16; ++r) {
        int hwl = cg * 16 + r;
        xTb[(size_t)(b * HW + hw0 + hwl) * C + lane] = f2bf(lds[lane][hwl]);
    }
}

// ---------------------------------------------------------------------------
// Kernel 2: repack w (Cout,C,3,3) fp32 -> wB[o][K] bf16, K = tap*64 + c.
// ---------------------------------------------------------------------------
__global__ __launch_bounds__(256) void k_prep_w(const float* __restrict__ w,
                                                ushort* __restrict__ wB) {
    int idx = blockIdx.x * 256 + threadIdx.x;
    if (idx >= COUT * KDIM) return;
    int o = idx / KDIM;
    int Kx = idx % KDIM;
    int k = Kx >> 6;
    int c = Kx & 63;
    wB[idx] = f2bf(w[(size_t)(o * C + c) * KK + k]);
}

// ---------------------------------------------------------------------------
// Kernel 2b: repack ow (27,C,3,3) fp32 -> awB[32][576] bf16 (rows 27..31 = 0),
// K = tap*64 + c  (must match k_om's B-fragment K indexing).
// ---------------------------------------------------------------------------
__global__ __launch_bounds__(256) void k_prep_aw(const float* __restrict__ ow,
                                                 ushort* __restrict__ awB) {
    int idx = blockIdx.x * 256 + threadIdx.x;  // o*576 + K
    if (idx >= 32 * KDIM) return;
    int o = idx / KDIM;
    int Kx = idx % KDIM;
    int tap = Kx >> 6;
    int c = Kx & 63;
    float v = (o < OC) ? ow[((size_t)o * C + c) * KK + tap] : 0.0f;
    awB[idx] = f2bf(v);
}

// ---------------------------------------------------------------------------
// Kernel 3: offset/mask conv as im2col GEMM (unchanged).
// ---------------------------------------------------------------------------
__global__ __launch_bounds__(256) void k_om(const ushort* __restrict__ xTb,
                                            const ushort* __restrict__ awB,
                                            const float* __restrict__ ob,
                                            float* __restrict__ om) {
    __shared__ __align__(16) char xwin[3 * 66 * 128];  // 25344 B
    int tid = threadIdx.x;
    int lane = tid & 63;
    int wv = tid >> 6;
    int blk = blockIdx.x;  // b*256 + h*2 + (w0/64)
    int b = blk >> 8;
    int h = (blk >> 1) & 127;
    int w0 = (blk & 1) * 64;

    const ushort* xb = xTb + (size_t)b * (HW * C);
    int ch2 = tid & 31;
#pragma unroll
    for (int it = 0; it < 25; ++it) {
        int pi = it * 8 + (tid >> 5);
        if (pi < 198) {
            int row = pi / 66;
            int col = pi - row * 66;
            int y = h - 1 + row;
            int xc = w0 - 1 + col;
            unsigned v = 0;
            if ((unsigned)y < H && (unsigned)xc < W)
                v = *(const unsigned*)(xb + ((size_t)(y * W + xc) << 6) + ch2 * 2);
            int byte = (pi * 128 + ch2 * 4) ^ ((col & 7) << 4);
            *(unsigned*)(xwin + byte) = v;
        }
    }
    __syncthreads();

    f32x4 acc0 = {0.f, 0.f, 0.f, 0.f};
    f32x4 acc1 = {0.f, 0.f, 0.f, 0.f};
    int pixl = lane & 15;
    int q = lane >> 4;
    int base_col = wv * 16 + pixl;
    const ushort* a0 = awB + (size_t)pixl * KDIM + q * 8;
    const ushort* a1 = awB + (size_t)(16 + pixl) * KDIM + q * 8;
#pragma unroll
    for (int s = 0; s < 18; ++s) {
        int tap = s >> 1;
        int row = tap / 3;
        int cs = tap - row * 3;
        int col = base_col + cs;
        int c0b = ((s & 1) * 32 + q * 8) * 2;
        int byte = (((row * 66 + col) << 7) + c0b) ^ ((col & 7) << 4);
        s16x8 bfrag = *(const s16x8*)(xwin + byte);
        s16x8 af0 = *(const s16x8*)(a0 + s * 32);
        s16x8 af1 = *(const s16x8*)(a1 + s * 32);
        acc0 = __builtin_amdgcn_mfma_f32_16x16x32_bf16(af0, bfrag, acc0, 0, 0, 0);
        acc1 = __builtin_amdgcn_mfma_f32_16x16x32_bf16(af1, bfrag, acc1, 0, 0, 0);
    }

    int pix = wv * 16 + pixl;
#pragma unroll
    for (int j = 0; j < 4; ++j) {
        int oc = q * 4 + j;
        om[(((size_t)b * OC + oc) * H + h) * W + w0 + pix] = acc0[j] + ob[oc];
        int oc1 = 16 + q * 4 + j;
        if (oc1 < OC)
            om[(((size_t)b * OC + oc1) * H + h) * W + w0 + pix] = acc1[j] + ob[oc1];
    }
}

// ---------------------------------------------------------------------------
// Kernel 4: fused deformable sampling + MFMA einsum.
//  A0: per (pixel,tap): 2 ROW-BASE byte offsets (row = 2 adjacent column
//      slots = 256B contiguous) + 4 slot weights (validity/mask folded).
//  A1: per pixel, batch-issue 18 global_load_dword (rowbase + 4*lane):
//      lanes<32 carry slot0 (2 ch each), lanes>=32 slot1. Blend slot-partials,
//      combine halves via shfl_xor(32), cvt_pk to bf16, half-wave ds_write_b32.
//      ~18-deep MLP, no readfirstlane chains.
//  B : 18 x mfma_f32_16x16x32_bf16 per wave.
// ---------------------------------------------------------------------------
__global__ __launch_bounds__(256, 6) void k_main(const ushort* __restrict__ xTb,
                                                 const float* __restrict__ om,
                                                 const ushort* __restrict__ wB,
                                                 const float* __restrict__ bias,
                                                 float* __restrict__ out) {
    __shared__ __align__(16) char smem[NPIX * LDSROW];  // 18432 B
    __shared__ float4 meta_w[NPAIR];                    // 2304 B
    __shared__ int2 meta_o[NPAIR];                      // 1152 B

    int tid = threadIdx.x;
    int lane = tid & 63;
    int wv = tid >> 6;
    int pb = blockIdx.x * NPIX;
    int b = pb >> 14;
    int rem = pb & (HW - 1);
    int h = rem >> 7;
    int w0 = rem & (W - 1);

    // ---- Phase A0: per-(pixel,tap) slot metadata ----
    if (tid < NPAIR) {
        int k = tid >> 4;
        int p = tid & 15;
        int dh = k / 3 - 1;
        int dw = k % 3 - 1;
        const float* o0 = om + ((size_t)b * OC) * HW + h * W + w0 + p;
        float offx = o0[(size_t)k * HW];
        float offy = o0[(size_t)(KK + k) * HW];
        float mlog = o0[(size_t)(2 * KK + k) * HW];
        float mask = 1.0f / (1.0f + __expf(-mlog));
        float gx = (float)(w0 + p + dw) + offx;
        float gy = (float)(h + dh) + offy;
        float x0f = floorf(gx), y0f = floorf(gy);
        int x0 = (int)x0f, y0 = (int)y0f;
        int x1 = x0 + 1, y1 = y0 + 1;
        float wx1 = gx - x0f, wy1 = gy - y0f;
        float wx0 = 1.0f - wx1, wy0 = 1.0f - wy1;
        float rw0 = ((unsigned)y0 < H) ? wy0 * mask : 0.0f;
        float rw1 = ((unsigned)y1 < H) ? wy1 * mask : 0.0f;
        int y0c = min(max(y0, 0), H - 1), y1c = min(max(y1, 0), H - 1);
        int colbase = min(max(x0, 0), W - 2);
        float cw0 = 0.0f, cw1 = 0.0f;
        if ((unsigned)x0 < W) { if (x0 == colbase) cw0 += wx0; else cw1 += wx0; }
        if ((unsigned)x1 < W) { if (x1 == colbase) cw0 += wx1; else cw1 += wx1; }
        // (slot0*row0, slot1*row0, slot0*row1, slot1*row1)
        meta_w[tid] = make_float4(rw0 * cw0, rw0 * cw1, rw1 * cw0, rw1 * cw1);
        meta_o[tid] = make_int2((y0c * W + colbase) * (C * 2),
                                (y1c * W + colbase) * (C * 2));
    }
    __syncthreads();

    // ---- Phase A1: batched full-wave row gathers ----
    const char* xbase = (const char*)(xTb + (size_t)b * (HW * C));
    bool lo_half = lane < 32;
#pragma unroll
    for (int pp = 0; pp < 4; ++pp) {
        int p = wv * 4 + pp;
        unsigned d0[KK], d1[KK];
        float wa[KK], wb[KK];
#pragma unroll
        for (int k = 0; k < KK; ++k) {
            int pair = k * 16 + p;
            float4 mw = meta_w[pair];
            int2 mo = meta_o[pair];
            wa[k] = lo_half ? mw.x : mw.y;  // row0 weight for my slot
            wb[k] = lo_half ? mw.z : mw.w;  // row1 weight for my slot
            d0[k] = *(const unsigned*)(xbase + mo.x + lane * 4);
            d1[k] = *(const unsigned*)(xbase + mo.y + lane * 4);
        }
        int vlds = p * LDSROW + (((lane & 31) * 4) ^ ((p & 7) << 4));
#pragma unroll
        for (int k = 0; k < KK; ++k) {
            float a0 = __uint_as_float(d0[k] << 16);           // row0, even ch
            float a1 = __uint_as_float(d0[k] & 0xFFFF0000u);   // row0, odd ch
            float b0 = __uint_as_float(d1[k] << 16);           // row1, even ch
            float b1 = __uint_as_float(d1[k] & 0xFFFF0000u);   // row1, odd ch
            float p0 = a0 * wa[k] + b0 * wb[k];
            float p1 = a1 * wa[k] + b1 * wb[k];
            float q0 = __shfl_xor(p0, 32, 64);  // other slot's partial
            float q1 = __shfl_xor(p1, 32, 64);
            float s0 = p0 + q0, s1 = p1 + q1;
            unsigned pk;
            asm("v_cvt_pk_bf16_f32 %0, %1, %2" : "=v"(pk) : "v"(s0), "v"(s1));
            if (lane < 32) *(unsigned*)(smem + vlds + k * 128) = pk;
        }
    }
    __syncthreads();

    // ---- Phase B: MFMA ----
    f32x4 acc;
#pragma unroll
    for (int j = 0; j < 4; ++j) acc[j] = bias[wv * 16 + (lane >> 4) * 4 + j];

    int pix = lane & 15;
    const ushort* wrow = wB + (size_t)(wv * 16 + pix) * KDIM + (lane >> 4) * 8;
#pragma unroll
    for (int s = 0; s < 18; ++s) {
        int kbyte = s * 64 + (lane >> 4) * 16;
        int byte = (pix * LDSROW + kbyte) ^ ((pix & 7) << 4);
        s16x8 bfrag = *(const s16x8*)(smem + byte);
        s16x8 afrag = *(const s16x8*)(wrow + s * 32);
        acc = __builtin_amdgcn_mfma_f32_16x16x32_bf16(afrag, bfrag, acc, 0, 0, 0);
    }

    float* obase = out + ((size_t)(b * COUT + wv * 16 + (lane >> 4) * 4) * HW) + h * W + w0;
#pragma unroll
    for (int j = 0; j < 4; ++j) obase[(size_t)j * HW + pix] = acc[j];
}

// ---------------------------------------------------------------------------
extern "C" void kernel_launch(void* const* d_in, const int* in_sizes, int n_in,
                              void* d_out, int out_size, void* d_ws, size_t ws_size,
                              hipStream_t stream) {
    const float* x = (const float*)d_in[0];
    const float* ow = (const float*)d_in[1];
    const float* ob = (const float*)d_in[2];
    const float* w = (const float*)d_in[3];
    const float* bias = (const float*)d_in[4];
    float* out = (float*)d_out;

    float* om = (float*)d_ws;                           // B*27*HW = 3538944 f
    ushort* xTb = (ushort*)(om + (size_t)B * OC * HW);  // B*HW*C ushort
    ushort* wB = xTb + (size_t)B * HW * C;              // 36864 ushort
    ushort* awB = wB + (size_t)COUT * KDIM;             // 18432 ushort
    // total ~31.1 MB

    hipLaunchKernelGGL(k_transpose_x, dim3(B * 256), dim3(256), 0, stream, x, xTb);
    hipLaunchKernelGGL(k_prep_w, dim3((COUT * KDIM + 255) / 256), dim3(256), 0,
                       stream, w, wB);
    hipLaunchKernelGGL(k_prep_aw, dim3((32 * KDIM + 255) / 256), dim3(256), 0,
                       stream, ow, awB);
    hipLaunchKernelGGL(k_om, dim3(B * H * 2), dim3(256), 0, stream, xTb, awB, ob, om);
    hipLaunchKernelGGL(k_main, dim3(B * HW / NPIX), dim3(256), 0, stream,
                       xTb, om, wB, bias, out);
}